// Round 9
// baseline (38.337 us; speedup 1.0000x reference)
//
#include <hip/hip_runtime.h>
#include <math.h>

#define KC     10      // clusters
#define BLOCK  256
#define WPB    4       // waves per block
#define NQ     (3*KC)  // pos[10], neg[10], cnt[10]
#define NBLK   512     // 2 blocks/CU (LDS-limited), exactly co-resident
#define BLOCKF 512     // finalize threads
#define TROWS  64      // rows per wave-tile (full row per lane)

typedef float v2f __attribute__((ext_vector_type(2)));
union F4 { float4 f; v2f h[2]; };

// DPP add: x += lane-permuted x. VALU pipe (no DS).
template<int CTRL>
__device__ __forceinline__ float dppadd(float x) {
    int y = __builtin_amdgcn_update_dpp(0, __float_as_int(x), CTRL, 0xF, 0xF, true);
    return x + __int_as_float(y);
}
// full row-of-16 allreduce: quad xor1, quad xor2, half_mirror, mirror
__device__ __forceinline__ float rowreduce(float x) {
    x = dppadd<0xB1>(x);    // quad_perm [1,0,3,2]  (xor 1)
    x = dppadd<0x4E>(x);    // quad_perm [2,3,0,1]  (xor 2)
    x = dppadd<0x141>(x);   // row_half_mirror      (quad swap in octet)
    x = dppadd<0x140>(x);   // row_mirror           (octet swap in row)
    return x;
}

// ---------------------------------------------------------------------------
// Full-row-per-lane streaming kernel.
//  - 64-row tile per wave staged via global_load_lds (16B, direct to LDS,
//    no ds_write, no VGPR round-trip). XOR swizzle applied on the GLOBAL
//    source address (LDS dest stays linear, as HW requires): LDS slot
//    (row r, cs) holds row r's actual chunk cs ^ (r&15).
//  - Lane l computes row l's 10 dots by looping chunk s=0..15: reads its
//    float4 at slot s^(l&15) (~conflict-free), FMAs against centers[k][s].
//    s is WAVE-UNIFORM -> centers come from SGPRs (s_load, SMEM pipe):
//    center LDS traffic of the old structure (40 ds_read/32 rows) -> 0.
//  - Per-lane stats for all 10 clusters (30 accs); DPP row-reduce epilogue.
//  - 2 waves/SIMD occupancy (LDS-limited) -> VGPR cap 256: no spill risk.
//  - NO __launch_bounds__ min-waves arg (r1/2/4: forces spill). NO
//    per-block threadfence finalize (r7: ~1us L2 walk per block).
// ---------------------------------------------------------------------------
__global__ __launch_bounds__(BLOCK) void cl_main(
    const float* __restrict__ feat, const int* __restrict__ pred,
    const float* __restrict__ centers, float* __restrict__ ws,
    int N, int nWaves, int nBlocks)
{
    __shared__ float tile[WPB][TROWS * 64];   // 4 x 16 KB
    __shared__ float rbuf[WPB * 4][NQ];       // 16 row-groups x 30

    const int tid  = threadIdx.x;
    const int lane = tid & 63;
    const int wave = tid >> 6;
    const int wgid = blockIdx.x * WPB + wave;
    const int l4   = lane & 15;
    const int rOff = lane >> 4;               // row offset within group-of-4

    float pos[KC], neg[KC], cnt[KC];
#pragma unroll
    for (int k = 0; k < KC; ++k) { pos[k] = 0.f; neg[k] = 0.f; cnt[k] = 0.f; }

    const int nTiles = (N + TROWS - 1) / TROWS;
    for (int t = wgid; t < nTiles; t += nWaves) {
        const int base = t * TROWS;

        // ---- stage 64 rows: staging inst i writes LDS slots i*64+lane ----
        // slot S holds (r = S>>4, cs = S&15) -> actual chunk cs ^ (r&15)
#pragma unroll
        for (int i = 0; i < 16; ++i) {
            const int r  = i * 4 + rOff;              // 0..63
            const int rg = base + r;
            const int rc = rg < N ? rg : N - 1;
            const int c  = l4 ^ (r & 15);             // pre-swizzled source
            const float* gp = feat + (size_t)rc * 64 + c * 4;
            __builtin_amdgcn_global_load_lds(
                (const __attribute__((address_space(1))) unsigned int*)gp,
                (__attribute__((address_space(3))) unsigned int*)&tile[wave][i * 256],
                16, 0, 0);
        }

        const int myrow = base + lane;
        const int myrc  = myrow < N ? myrow : N - 1;
        const int pcur  = pred[myrc];
        const float actf = myrow < N ? 1.f : 0.f;

        asm volatile("s_waitcnt vmcnt(0)" ::: "memory");

        // ---- dot products: lane owns row `lane`; s is wave-uniform ----
        v2f dot[KC];
#pragma unroll
        for (int k = 0; k < KC; ++k) dot[k] = (v2f)(0.f);

        const float* tl = &tile[wave][lane * 64];
        for (int s = 0; s < 16; ++s) {
            F4 f;
            f.f = *(const float4*)(tl + ((s ^ l4) << 2));   // swizzled read
#pragma unroll
            for (int k = 0; k < KC; ++k) {
                F4 cv;
                cv.f = ((const float4*)centers)[k * 16 + s]; // uniform -> s_load
                dot[k] += f.h[0] * cv.h[0];
                dot[k] += f.h[1] * cv.h[1];
            }
        }

        // ---- epilogue: 10 clusters for this lane's row ----
#pragma unroll
        for (int k = 0; k < KC; ++k) {
            const float d  = dot[k].x + dot[k].y;
            const float sc = fminf(fmaxf(d * 0.5f, -10.f), 10.f);
            const float e  = __expf(sc) * actf;
            const bool  h  = (pcur == k);
            neg[k] += e;
            pos[k] += h ? e : 0.f;
            cnt[k] += h ? actf : 0.f;
        }
    }

    // ---- in-wave reduce (DPP, VALU pipe): each row-of-16 -> one sum ----
#pragma unroll
    for (int k = 0; k < KC; ++k) {
        pos[k] = rowreduce(pos[k]);
        neg[k] = rowreduce(neg[k]);
        cnt[k] = rowreduce(cnt[k]);
    }
    if (l4 == 0) {
        const int rg = wave * 4 + rOff;       // 0..15
#pragma unroll
        for (int k = 0; k < KC; ++k) {
            rbuf[rg][k]          = pos[k];
            rbuf[rg][KC + k]     = neg[k];
            rbuf[rg][2 * KC + k] = cnt[k];
        }
    }
    __syncthreads();
    if (tid < NQ) {                           // block partial, layout [q][nBlocks]
        float s = 0.f;
#pragma unroll
        for (int r = 0; r < WPB * 4; ++r) s += rbuf[r][tid];
        ws[(size_t)tid * nBlocks + blockIdx.x] = s;
    }
}

// ---------------------------------------------------------------------------
// Finalize: one 512-thread block; 16-thread group per quantity (30 groups),
// float4 coalesced reads, fixed-order butterfly, thread 0 computes the loss.
// ---------------------------------------------------------------------------
__global__ __launch_bounds__(BLOCKF) void cl_final(
    const float* __restrict__ ws, float* __restrict__ out, int N, int nBlocks)
{
    const int tid = threadIdx.x;
    const int grp = tid >> 4, sub = tid & 15;   // 16 threads per quantity
    __shared__ float sq[NQ];

    float acc = 0.f;
    if (grp < NQ) {
        const float4* w4 = (const float4*)(ws + (size_t)grp * nBlocks);
        const int n4 = nBlocks >> 2;
        for (int i = sub; i < n4; i += 16) {
            const float4 v = w4[i];
            acc += (v.x + v.y) + (v.z + v.w);
        }
    }
    acc += __shfl_xor(acc, 1, 64);
    acc += __shfl_xor(acc, 2, 64);
    acc += __shfl_xor(acc, 4, 64);
    acc += __shfl_xor(acc, 8, 64);
    if (grp < NQ && sub == 0) sq[grp] = acc;
    __syncthreads();

    if (tid == 0) {
        float tot = 0.f;
        int nv = 0;
#pragma unroll
        for (int k = 0; k < KC; ++k) {
            const float pos_s = sq[k];
            const float neg_s = sq[KC + k];
            const float cnt   = sq[2 * KC + k];
            const float neg = neg_s / (float)N;             // e.mean(axis=0)
            const float pos = pos_s / fmaxf(cnt, 1.f);      // sum / max(count,1)
            const float lt  = -logf(pos / (neg + 1e-8f));
            const bool valid = (cnt > 0.f) && (cnt < (float)N) &&
                               (pos > 1e-8f) && (neg > 1e-8f) && isfinite(lt);
            if (valid) { tot += lt; ++nv; }
        }
        out[0] = (nv > 0 ? tot / (float)nv : 0.f) * 5.0f;   // * weight
    }
}

extern "C" void kernel_launch(void* const* d_in, const int* in_sizes, int n_in,
                              void* d_out, int out_size, void* d_ws, size_t ws_size,
                              hipStream_t stream) {
    const float* feat    = (const float*)d_in[0];
    const int*   pred    = (const int*)d_in[1];
    const float* centers = (const float*)d_in[2];
    float*       out     = (float*)d_out;
    const int N = in_sizes[1];          // 500000

    int nBlocks = NBLK;
    const int maxB = (int)(ws_size / (NQ * sizeof(float)));
    if (nBlocks > maxB) nBlocks = maxB & ~3;
    if (nBlocks < 4) nBlocks = 4;
    const int nWaves = nBlocks * WPB;

    hipLaunchKernelGGL(cl_main, dim3(nBlocks), dim3(BLOCK), 0, stream,
                       feat, pred, centers, (float*)d_ws, N, nWaves, nBlocks);
    hipLaunchKernelGGL(cl_final, dim3(1), dim3(BLOCKF), 0, stream,
                       (const float*)d_ws, out, N, nBlocks);
}